// Round 4
// baseline (26.520 us; speedup 1.0000x reference)
//
#include <hip/hip_runtime.h>
#include <math.h>

// BrownianKernelLayer: K[i,j] = 0.5 * sum_d (|x_id|^p + |X2_jd|^p - |x_id - X2_jd|^p)
// p = 2 * softplus(log_H), H = p/2.  N=M=2048, D=16, fp32 in/out.
//
// v4: zero transcendentals in the inner loop.
//   s = u^2 + 1e-30 = m * 2^(b-127),  m in [1,2)  (IEEE bit split, 2 VALU ops)
//   s^H = m^H * 2^(H*(b-127))
//     m^H        : degree-4 polynomial, coefficients fitted at runtime from H
//                  (Chebyshev interpolation on [1,2], rel err ~1.6e-5)
//     2^(H(b-127)): 256-entry LDS table indexed by raw biased exponent b.
//                   b concentrates in ~10 consecutive values per wave ->
//                   consecutive banks + broadcast -> near-conflict-free gather.
// Per term: 10 full-rate VALU + 1 ds_read_b32, vs 3 VALU + 2 trans (~28cy each).

#define D_DIM 16
#define BLK 64

__device__ __forceinline__ float powH(float v, float H) {
    // v > 0; v^H = exp2(H * log2(v)) -- setup only (5 calls/thread)
    return __builtin_amdgcn_exp2f(H * __builtin_amdgcn_logf(v));
}

__global__ __launch_bounds__(256) void fbm_kernel(
    const float* __restrict__ x,    // [N, 16]
    const float* __restrict__ X2,   // [M, 16]
    const float* __restrict__ logH, // [1]
    float* __restrict__ out,        // [N, M]
    int N, int M)
{
    __shared__ float tbl[256];         // 2^(H*(b-127)) by biased exponent b
    __shared__ float xs[D_DIM][BLK];   // transposed x tile
    __shared__ float ys[D_DIM][BLK];   // transposed X2 tile
    __shared__ float t1s[BLK];
    __shared__ float t2s[BLK];

    const int tid  = threadIdx.x;
    const int brow = blockIdx.y * BLK;
    const int bcol = blockIdx.x * BLK;

    const float H = log1pf(expf(logH[0]));  // softplus(log_H)

    // ---- fit degree-4 poly for m^H on [1,2], Chebyshev nodes t = m-1.5
    const float T1 = 0.475528258f, T2 = 0.293892626f;  // 0.5*cos(18deg), 0.5*cos(54deg)
    float f0 = powH(1.5f + T1, H);
    float f1 = powH(1.5f + T2, H);
    float f2 = powH(1.5f,      H);
    float f3 = powH(1.5f - T2, H);
    float f4 = powH(1.5f - T1, H);
    float s1 = 0.5f * (f0 + f4), d1 = 0.5f * (f0 - f4);
    float s2 = 0.5f * (f1 + f3), d2 = 0.5f * (f1 - f3);
    float u1 = T1 * T1, u2 = T2 * T2;
    // even part: f2 + e1*t^2 + e2*t^4
    float A = s1 - f2, B = s2 - f2;
    float det = u1 * u2 * (u2 - u1);
    float e1 = (A * u2 * u2 - B * u1 * u1) / det;
    float e2 = (B * u1 - A * u2) / det;
    // odd part: t*(o0 + o1*t^2)
    float Ap = d1 / T1, Bp = d2 / T2;
    float o1 = (Ap - Bp) / (u1 - u2);
    float o0 = Ap - o1 * u1;
    // shift t = m - 1.5 to monomial in m
    float a4 = e2;
    float a3 = o1 - 6.0f * e2;
    float a2 = e1 - 4.5f * o1 + 13.5f * e2;
    float a1 = o0 - 3.0f * e1 + 6.75f * o1 - 13.5f * e2;
    float a0 = f2 - 1.5f * o0 + 2.25f * e1 - 3.375f * o1 + 5.0625f * e2;

    // ---- fill exponent table: tbl[b] = 2^(H*(b-127))
    tbl[tid & 255] = __builtin_amdgcn_exp2f(H * ((float)(tid & 255) - 127.0f));

    // ---- stage tiles (raw values)
    {
        float4 vx = ((const float4*)(x  + (size_t)brow * D_DIM))[tid];
        float4 vy = ((const float4*)(X2 + (size_t)bcol * D_DIM))[tid];
        int r  = tid >> 2;
        int d0 = (tid & 3) << 2;
        xs[d0 + 0][r] = vx.x; xs[d0 + 1][r] = vx.y;
        xs[d0 + 2][r] = vx.z; xs[d0 + 3][r] = vx.w;
        ys[d0 + 0][r] = vy.x; ys[d0 + 1][r] = vy.y;
        ys[d0 + 2][r] = vy.z; ys[d0 + 3][r] = vy.w;
    }
    __syncthreads();

    #define POWP(S_) ({ \
        unsigned bits_ = __float_as_uint(S_); \
        float m_ = __uint_as_float((bits_ & 0x007FFFFFu) | 0x3F800000u); \
        float g_ = fmaf(fmaf(fmaf(fmaf(a4, m_, a3), m_, a2), m_, a1), m_, a0); \
        g_ * tbl[bits_ >> 23]; })

    // ---- per-row self terms t1 (x rows) / t2 (X2 rows)
    if (tid < 128) {
        int r = tid & 63;
        const float (*src)[BLK] = (tid < 64) ? xs : ys;
        float s = 0.0f;
        #pragma unroll
        for (int d = 0; d < D_DIM; ++d) {
            float v = src[d][r];
            float sq = fmaf(v, v, 1e-30f);
            s += POWP(sq);
        }
        if (tid < 64) t1s[r] = s; else t2s[r] = s;
    }
    __syncthreads();

    // ---- main: 4x4 outputs per thread; 16x16 thread grid covers 64x64
    const int ti = tid >> 4;
    const int tj = tid & 15;

    float acc[4][4] = {};

    #define TERM(A_, B_, R_, C_) { \
        float u_ = (A_) - (B_); \
        float s_ = fmaf(u_, u_, 1e-30f); \
        unsigned bits_ = __float_as_uint(s_); \
        float m_ = __uint_as_float((bits_ & 0x007FFFFFu) | 0x3F800000u); \
        float g_ = fmaf(fmaf(fmaf(fmaf(a4, m_, a3), m_, a2), m_, a1), m_, a0); \
        acc[R_][C_] = fmaf(g_, tbl[bits_ >> 23], acc[R_][C_]); }

    #pragma unroll
    for (int d = 0; d < D_DIM; ++d) {
        float4 xa = *(const float4*)&xs[d][ti * 4];
        float4 xb = *(const float4*)&ys[d][tj * 4];
        float A0 = xa.x, A1 = xa.y, A2 = xa.z, A3 = xa.w;
        float B0 = xb.x, B1 = xb.y, B2 = xb.z, B3 = xb.w;

        TERM(A0, B0, 0, 0) TERM(A0, B1, 0, 1) TERM(A0, B2, 0, 2) TERM(A0, B3, 0, 3)
        TERM(A1, B0, 1, 0) TERM(A1, B1, 1, 1) TERM(A1, B2, 1, 2) TERM(A1, B3, 1, 3)
        TERM(A2, B0, 2, 0) TERM(A2, B1, 2, 1) TERM(A2, B2, 2, 2) TERM(A2, B3, 2, 3)
        TERM(A3, B0, 3, 0) TERM(A3, B1, 3, 1) TERM(A3, B2, 3, 2) TERM(A3, B3, 3, 3)
    }
    #undef TERM

    // ---- epilogue: K = 0.5*(t1[i] + t2[j] - t3)
    float t2v0 = t2s[tj * 4 + 0];
    float t2v1 = t2s[tj * 4 + 1];
    float t2v2 = t2s[tj * 4 + 2];
    float t2v3 = t2s[tj * 4 + 3];

    #pragma unroll
    for (int a = 0; a < 4; ++a) {
        float t1v = t1s[ti * 4 + a];
        float4 o;
        o.x = 0.5f * (t1v + t2v0 - acc[a][0]);
        o.y = 0.5f * (t1v + t2v1 - acc[a][1]);
        o.z = 0.5f * (t1v + t2v2 - acc[a][2]);
        o.w = 0.5f * (t1v + t2v3 - acc[a][3]);
        int gi = brow + ti * 4 + a;
        *(float4*)(out + (size_t)gi * M + bcol + tj * 4) = o;
    }
}

extern "C" void kernel_launch(void* const* d_in, const int* in_sizes, int n_in,
                              void* d_out, int out_size, void* d_ws, size_t ws_size,
                              hipStream_t stream) {
    const float* x    = (const float*)d_in[0];
    const float* X2   = (const float*)d_in[1];
    const float* logH = (const float*)d_in[2];
    float* out = (float*)d_out;

    int N = in_sizes[0] / D_DIM;
    int M = in_sizes[1] / D_DIM;

    dim3 grid(M / BLK, N / BLK);
    dim3 block(256);
    fbm_kernel<<<grid, block, 0, stream>>>(x, X2, logH, out, N, M);
}